// Round 6
// baseline (318.309 us; speedup 1.0000x reference)
//
#include <hip/hip_runtime.h>
#include <hip/hip_bf16.h>

#define N_NODES 100000
#define N_EDGES 1600000
#define N_HOPS 3
#define D_HID 256
#define N_GRAPHS 64

#define CHUNK 32
#define NCHUNK 3125          /* 100000/32 */
#define FG 512               /* fused grid */

#define NB 625               /* node buckets */
#define RB 160               /* nodes per bucket (5 chunks) */
#define NSH 4                /* cursor shadows */
#define CAP 2400             /* record capacity per (shadow,bucket); mean 1920, sigma~44 */
#define SGRID 512            /* scatter blocks: exactly 2/CU, no tail */
#define STHREADS 512
#define EPBK (N_EDGES * N_HOPS / SGRID)   /* 9375 edges per block, ~60B/bucket-region */

// ws layout (total ~36.9 MB):
//  [0, 12.8MB)        ct bf16 A-frag [NCHUNK][4][64][8]
//  [12.8MB, 36.8MB)   records u32 [NSH][NB][CAP] = 24.0MB   (phase A/B)
//    overlay: s_part bf16 [FG][64*256] = 16.8MB             (fused onward)
//  [36.8MB, ...)      cursors u32[NSH*NB] | tg f32[64] | s_sum f32[16384]
#define CT_OFF    0u
#define REC_OFF   12800000u
#define SPART_OFF REC_OFF
#define SMALL_OFF 36800000u
#define CUR_OFF   SMALL_OFF
#define TG_OFF    (SMALL_OFF + 16384u)
#define SSUM_OFF  (SMALL_OFF + 32768u)

typedef __attribute__((ext_vector_type(4))) float f32x4;
typedef __attribute__((ext_vector_type(8))) short s16x8;

__device__ __forceinline__ unsigned short f2bf_rne(float f) {
    union { float f; unsigned u; } v; v.f = f;
    unsigned r = v.u + 0x7FFFu + ((v.u >> 16) & 1u);
    return (unsigned short)(r >> 16);
}
__device__ __forceinline__ float bf2f(unsigned short s) {
    union { float f; unsigned u; } v; v.u = ((unsigned)s) << 16;
    return v.f;
}
__device__ __forceinline__ unsigned pk_rne(float lo, float hi) {
    return ((unsigned)f2bf_rne(hi) << 16) | (unsigned)f2bf_rne(lo);
}

// ---- Phase A: bin edges into per-(shadow,bucket) record ranges.
// Flat hop-folded index, 512 blocks x 512 threads = exactly 2 blocks/CU
// (no dispatch tail — round-5 scatter lost ~1/3 to a 3rd block round).
// Streaming two-pass (no register buffering -> no spill); pass-2 re-read
// is L3-hot. Per-block bucket appends ~15 recs (60B) — above the partial-
// line write-churn threshold found in round 4.
__global__ __launch_bounds__(STHREADS) void scatter_kernel(
    const int* __restrict__ ei, const float* __restrict__ ew,
    const int* __restrict__ batch, const float* __restrict__ pw,
    unsigned* __restrict__ cursors, unsigned* __restrict__ records) {
    __shared__ unsigned cnt[NB], basearr[NB];
    const int tid = threadIdx.x;
    const int sh = blockIdx.x & (NSH - 1);
    const int e0 = blockIdx.x * EPBK, e1 = e0 + EPBK;

    for (int i = tid; i < NB; i += STHREADS) cnt[i] = 0u;
    __syncthreads();

    // pass 1: histogram on src only
    for (int e = e0 + tid; e < e1; e += STHREADS) {
        unsigned hop = (unsigned)e / N_EDGES;
        int r = e - (int)hop * N_EDGES;
        int src = ei[(size_t)hop * 2 * N_EDGES + r];
        atomicAdd(&cnt[(unsigned)src / RB], 1u);
    }
    __syncthreads();
    for (int i = tid; i < NB; i += STHREADS) {
        unsigned c = cnt[i];
        basearr[i] = c ? atomicAdd(&cursors[sh * NB + i], c) : 0u;
        cnt[i] = 0u;  // reuse as within-block placement counter
    }
    __syncthreads();

    // pass 2: re-read (L3-hot), build record, place into reserved slot
    const float pw1 = pw[1], pw2 = pw[2], pw3 = pw[3];
    for (int e = e0 + tid; e < e1; e += STHREADS) {
        unsigned hop = (unsigned)e / N_EDGES;
        int r = e - (int)hop * N_EDGES;
        const int* sp = ei + (size_t)hop * 2 * N_EDGES;
        int src = sp[r];
        int dst = sp[N_EDGES + r];
        float wv = ew[(size_t)hop * N_EDGES + r];
        float pwh = hop == 0 ? pw1 : (hop == 1 ? pw2 : pw3);
        unsigned b = (unsigned)src / RB;
        unsigned o = atomicAdd(&cnt[b], 1u);
        records[((size_t)sh * NB + b) * CAP + basearr[b] + o] =
            ((unsigned)f2bf_rne(pwh * wv) << 16) |
            (unsigned)(((unsigned)src - b * RB) * 64 + batch[dst]);
    }
}

// ---- Phase B: one block per bucket. LDS f32 tile [160][65] (slot = m+(m>>6)).
// Replays records (uint4 loads) with LDS atomics, adds pw0 term, emits ct
// (MFMA-A bf16 layout) + tg column sums. coeff never touches HBM.
__global__ __launch_bounds__(512) void phaseB_kernel(
    const int* __restrict__ batch, const float* __restrict__ pw,
    const unsigned* __restrict__ cursors, const unsigned* __restrict__ records,
    unsigned short* __restrict__ ct, float* __restrict__ tg) {
    __shared__ float tile[RB * 65];
    const int tid = threadIdx.x;
    const int b = blockIdx.x;

    for (int i = tid; i < RB * 65; i += 512) tile[i] = 0.f;
    __syncthreads();

    if (tid < RB) atomicAdd(&tile[tid * 65 + batch[b * RB + tid]], pw[0]);

    for (int sh = 0; sh < NSH; sh++) {
        unsigned n = cursors[sh * NB + b];
        const unsigned* rp = records + ((size_t)sh * NB + b) * CAP;
        unsigned n4 = n >> 2;
        for (unsigned i = tid; i < n4; i += 512) {
            uint4 r4 = *(const uint4*)(rp + 4 * i);
            unsigned m0 = r4.x & 0x3FFFu, m1 = r4.y & 0x3FFFu;
            unsigned m2 = r4.z & 0x3FFFu, m3 = r4.w & 0x3FFFu;
            atomicAdd(&tile[m0 + (m0 >> 6)], bf2f((unsigned short)(r4.x >> 16)));
            atomicAdd(&tile[m1 + (m1 >> 6)], bf2f((unsigned short)(r4.y >> 16)));
            atomicAdd(&tile[m2 + (m2 >> 6)], bf2f((unsigned short)(r4.z >> 16)));
            atomicAdd(&tile[m3 + (m3 >> 6)], bf2f((unsigned short)(r4.w >> 16)));
        }
        unsigned i = 4 * n4 + tid;
        if (i < n) {
            unsigned r = rp[i];
            unsigned m = r & 0x3FFFu;
            atomicAdd(&tile[m + (m >> 6)], bf2f((unsigned short)(r >> 16)));
        }
    }
    __syncthreads();

    if (tid < 256) {
        const int gt = tid >> 6, l = tid & 63, q = l >> 4, c = l & 15;
        for (int cc = 0; cc < 5; cc++) {
            s16x8 v;
#pragma unroll
            for (int j = 0; j < 8; j++)
                v[j] = (short)f2bf_rne(tile[(cc * 32 + 8 * q + j) * 65 + 16 * gt + c]);
            *(s16x8*)&ct[(((size_t)(b * 5 + cc) * 4 + gt) * 64 + l) * 8] = v;
        }
    }
    if (tid < 64) {
        float sum = 0.f;
        for (int s = 0; s < RB; s++) sum += tile[s * 65 + tid];
        atomicAdd(&tg[tid], sum);
    }
}

// ---- Fused MFMA kernel: per 32-node chunk,
//   U = relu(X@W1 + b1)   (W1 B-frags persistent in registers)
//   S += Ct^T @ U
__global__ __launch_bounds__(256, 2) void fused_kernel(
    const float* __restrict__ x,
    const float* __restrict__ w1,
    const float* __restrict__ b1,
    const unsigned short* __restrict__ ct,
    unsigned short* __restrict__ s_part) {

    __shared__ __align__(16) unsigned short Ut[256 * 40];     // 20 KB
    __shared__ __align__(16) unsigned short x_lds[32 * 136];  // 8.7 KB
    __shared__ __align__(16) unsigned short ct_lds[2048];     // 4 KB

    const int tid = threadIdx.x;
    const int w = tid >> 6, l = tid & 63, q = l >> 4, c = l & 15;
    const int wcol = w * 64;
    const int sr = tid >> 3, sk = (tid & 7) * 16;

    s16x8 w1f[4][4];
#pragma unroll
    for (int nt = 0; nt < 4; nt++)
#pragma unroll
        for (int ks = 0; ks < 4; ks++) {
            s16x8 v;
#pragma unroll
            for (int j = 0; j < 8; j++)
                v[j] = (short)f2bf_rne(w1[(size_t)(32 * ks + 8 * q + j) * 256 + wcol + 16 * nt + c]);
            w1f[nt][ks] = v;
        }

    float bias[4];
#pragma unroll
    for (int nt = 0; nt < 4; nt++) bias[nt] = b1[wcol + 16 * nt + c];

    f32x4 sacc[4][4];
#pragma unroll
    for (int gt = 0; gt < 4; gt++)
#pragma unroll
        for (int nt = 0; nt < 4; nt++) sacc[gt][nt] = (f32x4)0.f;

    uint4 xp0, xp1;
    s16x8 ctp;

#define PREF(CI)                                                              \
    {                                                                         \
        const float4* p = (const float4*)&x[(size_t)((CI) * 32 + sr) * 128 + sk]; \
        float4 v0 = p[0], v1 = p[1], v2 = p[2], v3 = p[3];                    \
        xp0.x = pk_rne(v0.x, v0.y); xp0.y = pk_rne(v0.z, v0.w);               \
        xp0.z = pk_rne(v1.x, v1.y); xp0.w = pk_rne(v1.z, v1.w);               \
        xp1.x = pk_rne(v2.x, v2.y); xp1.y = pk_rne(v2.z, v2.w);               \
        xp1.z = pk_rne(v3.x, v3.y); xp1.w = pk_rne(v3.z, v3.w);               \
        ctp = *(const s16x8*)&ct[(size_t)(CI) * 2048 + tid * 8];              \
    }

    int ci = blockIdx.x;
    if (ci < NCHUNK) PREF(ci);

    for (; ci < NCHUNK; ci += FG) {
        *(uint4*)&x_lds[sr * 136 + sk] = xp0;
        *(uint4*)&x_lds[sr * 136 + sk + 8] = xp1;
        *(s16x8*)&ct_lds[tid * 8] = ctp;
        __syncthreads();

        s16x8 af[2][4], ctf[4];
#pragma unroll
        for (int mt = 0; mt < 2; mt++)
#pragma unroll
            for (int ks = 0; ks < 4; ks++)
                af[mt][ks] = *(const s16x8*)&x_lds[(16 * mt + c) * 136 + 32 * ks + 8 * q];
#pragma unroll
        for (int gt = 0; gt < 4; gt++)
            ctf[gt] = *(const s16x8*)&ct_lds[(gt * 64 + l) * 8];
        __syncthreads();

        if (ci + FG < NCHUNK) PREF(ci + FG);

        f32x4 u[2][4];
#pragma unroll
        for (int mt = 0; mt < 2; mt++)
#pragma unroll
            for (int nt = 0; nt < 4; nt++) {
                f32x4 a; a[0] = a[1] = a[2] = a[3] = bias[nt];
                u[mt][nt] = a;
            }
#pragma unroll
        for (int ks = 0; ks < 4; ks++)
#pragma unroll
            for (int mt = 0; mt < 2; mt++)
#pragma unroll
                for (int nt = 0; nt < 4; nt++)
                    u[mt][nt] = __builtin_amdgcn_mfma_f32_16x16x32_bf16(
                        af[mt][ks], w1f[nt][ks], u[mt][nt], 0, 0, 0);

#pragma unroll
        for (int mt = 0; mt < 2; mt++)
#pragma unroll
            for (int nt = 0; nt < 4; nt++) {
                f32x4 v = u[mt][nt];
                uint2 d;
                d.x = pk_rne(fmaxf(v[0], 0.f), fmaxf(v[1], 0.f));
                d.y = pk_rne(fmaxf(v[2], 0.f), fmaxf(v[3], 0.f));
                *(uint2*)&Ut[(wcol + 16 * nt + c) * 40 + 16 * mt + 4 * q] = d;
            }

#pragma unroll
        for (int nt = 0; nt < 4; nt++) {
            s16x8 uf = *(const s16x8*)&Ut[(wcol + 16 * nt + c) * 40 + 8 * q];
#pragma unroll
            for (int gt = 0; gt < 4; gt++)
                sacc[gt][nt] = __builtin_amdgcn_mfma_f32_16x16x32_bf16(
                    ctf[gt], uf, sacc[gt][nt], 0, 0, 0);
        }
    }
#undef PREF

    unsigned short* my = s_part + (size_t)blockIdx.x * (64 * 256);
#pragma unroll
    for (int gt = 0; gt < 4; gt++)
#pragma unroll
        for (int nt = 0; nt < 4; nt++)
#pragma unroll
            for (int r = 0; r < 4; r++)
                my[(16 * gt + 4 * q + r) * 256 + wcol + 16 * nt + c] =
                    f2bf_rne(sacc[gt][nt][r]);
}

// 256 blocks: element range split 64-wide, FG dim split 4-way for parallelism
__global__ __launch_bounds__(256) void reduce_kernel(const unsigned short* __restrict__ s_part,
                                                     float* __restrict__ s_sum) {
    __shared__ float red[4][64];
    const int l = threadIdx.x & 63, p = threadIdx.x >> 6;
    const int e = blockIdx.x * 64 + l;
    float a0 = 0.f, a1 = 0.f, a2 = 0.f, a3 = 0.f;
    for (int b = p * (FG / 4); b < (p + 1) * (FG / 4); b += 4) {
        a0 += bf2f(s_part[(size_t)(b + 0) * 16384 + e]);
        a1 += bf2f(s_part[(size_t)(b + 1) * 16384 + e]);
        a2 += bf2f(s_part[(size_t)(b + 2) * 16384 + e]);
        a3 += bf2f(s_part[(size_t)(b + 3) * 16384 + e]);
    }
    red[p][l] = (a0 + a1) + (a2 + a3);
    __syncthreads();
    if (p == 0) s_sum[e] = (red[0][l] + red[1][l]) + (red[2][l] + red[3][l]);
}

__global__ void finalize_kernel(const float* __restrict__ s,
                                const float* __restrict__ t,
                                const float* __restrict__ w2,
                                const float* __restrict__ b2,
                                float* __restrict__ out) {
    __shared__ float red[128];
    const int g = blockIdx.x;
    const int f = threadIdx.x;

    float acc = t[g] * b2[f];
    for (int k = 0; k < D_HID; k++)
        acc += s[(size_t)g * 256 + k] * w2[(size_t)k * 128 + f];

    red[f] = acc;
    __syncthreads();
    for (int off = 64; off > 0; off >>= 1) {
        if (f < off) red[f] = fmaxf(red[f], red[f + off]);
        __syncthreads();
    }
    float mx = red[0];
    __syncthreads();
    red[f] = expf(acc - mx);
    __syncthreads();
    for (int off = 64; off > 0; off >>= 1) {
        if (f < off) red[f] += red[f + off];
        __syncthreads();
    }
    float lse = logf(red[0]);
    out[(size_t)g * 128 + f] = acc - mx - lse;
}

extern "C" void kernel_launch(void* const* d_in, const int* in_sizes, int n_in,
                              void* d_out, int out_size, void* d_ws, size_t ws_size,
                              hipStream_t stream) {
    const float* x     = (const float*)d_in[0];
    const int*   ei    = (const int*)d_in[1];
    const float* ew    = (const float*)d_in[2];
    const int*   batch = (const int*)d_in[3];
    const float* w1    = (const float*)d_in[4];
    const float* b1    = (const float*)d_in[5];
    const float* w2    = (const float*)d_in[6];
    const float* b2    = (const float*)d_in[7];
    const float* pw    = (const float*)d_in[8];
    float* out = (float*)d_out;

    unsigned short* ctp     = (unsigned short*)((char*)d_ws + CT_OFF);
    unsigned*       records = (unsigned*)((char*)d_ws + REC_OFF);
    unsigned short* s_part  = (unsigned short*)((char*)d_ws + SPART_OFF);
    unsigned*       cursors = (unsigned*)((char*)d_ws + CUR_OFF);
    float*          tgp     = (float*)((char*)d_ws + TG_OFF);
    float*          s_sum   = (float*)((char*)d_ws + SSUM_OFF);

    hipMemsetAsync(cursors, 0, NSH * NB * sizeof(unsigned), stream);
    hipMemsetAsync(tgp, 0, 64 * sizeof(float), stream);

    scatter_kernel<<<dim3(SGRID), STHREADS, 0, stream>>>(
        ei, ew, batch, pw, cursors, records);
    phaseB_kernel<<<dim3(NB), 512, 0, stream>>>(batch, pw, cursors, records, ctp, tgp);
    fused_kernel<<<dim3(FG), 256, 0, stream>>>(x, w1, b1, ctp, s_part);
    reduce_kernel<<<dim3(256), 256, 0, stream>>>(s_part, s_sum);
    finalize_kernel<<<dim3(64), 128, 0, stream>>>(s_sum, tgp, w2, b2, out);
}

// Round 7
// 256.288 us; speedup vs baseline: 1.2420x; 1.2420x over previous
//
#include <hip/hip_runtime.h>
#include <hip/hip_bf16.h>

#define N_NODES 100000
#define N_EDGES 1600000
#define N_HOPS 3
#define D_HID 256
#define N_GRAPHS 64

#define CHUNK 32
#define NCHUNK 3125          /* 100000/32 */
#define FG 512               /* fused grid */

#define NB 625               /* node buckets */
#define RB 160               /* nodes per bucket (5 chunks) */
#define NSH 4                /* cursor shadows */
#define CAP 2400             /* record capacity per (shadow,bucket); mean 1920, sigma~44 */
#define SGRID 512            /* scatter blocks: exactly 2/CU resident, ONE round */
#define SB 1024              /* scatter block threads (16 waves) */
#define EPBK (N_EDGES * N_HOPS / SGRID)   /* 9375 edges per block, exact */
#define EPT 10               /* ceil(9375/1024) buffered steps, last masked */

// ws layout (total ~36.9 MB):
//  [0, 12.8MB)        ct bf16 A-frag [NCHUNK][4][64][8]
//  [12.8MB, 36.8MB)   records u32 [NSH][NB][CAP] = 24.0MB   (phase A/B)
//    overlay: s_part bf16 [FG][64*256] = 16.8MB             (fused onward)
//  [36.8MB, ...)      cursors u32[NSH*NB] | tg f32[64] | s_sum f32[16384]
#define CT_OFF    0u
#define REC_OFF   12800000u
#define SPART_OFF REC_OFF
#define SMALL_OFF 36800000u
#define CUR_OFF   SMALL_OFF
#define TG_OFF    (SMALL_OFF + 16384u)
#define SSUM_OFF  (SMALL_OFF + 32768u)

typedef __attribute__((ext_vector_type(4))) float f32x4;
typedef __attribute__((ext_vector_type(8))) short s16x8;

__device__ __forceinline__ unsigned short f2bf_rne(float f) {
    union { float f; unsigned u; } v; v.f = f;
    unsigned r = v.u + 0x7FFFu + ((v.u >> 16) & 1u);
    return (unsigned short)(r >> 16);
}
__device__ __forceinline__ float bf2f(unsigned short s) {
    union { float f; unsigned u; } v; v.u = ((unsigned)s) << 16;
    return v.f;
}
__device__ __forceinline__ unsigned pk_rne(float lo, float hi) {
    return ((unsigned)f2bf_rne(hi) << 16) | (unsigned)f2bf_rne(lo);
}

// ---- Phase A: bin edges into per-(shadow,bucket) record ranges.
// Round-5 proven body (single-pass, register-buffered records, NON-TEMPORAL
// edge loads so the 57.6MB stream doesn't evict partial record lines from L2
// — dropping NT was round-6's 140MB WRITE blowup) + round-6's tail fix:
// flat 4.8M-edge range split over exactly 512 blocks -> one dispatch round.
__global__ __launch_bounds__(SB) void scatter_kernel(
    const int* __restrict__ ei, const float* __restrict__ ew,
    const int* __restrict__ batch, const float* __restrict__ pw,
    unsigned* __restrict__ cursors, unsigned* __restrict__ records) {
    __shared__ unsigned cnt[NB], basearr[NB];
    const int tid = threadIdx.x;
    const int sh = blockIdx.x & (NSH - 1);
    const int e0 = blockIdx.x * EPBK;

    if (tid < NB) cnt[tid] = 0u;
    __syncthreads();

    const float pw1 = pw[1], pw2 = pw[2], pw3 = pw[3];

    unsigned rec[EPT], bkt[EPT];
#pragma unroll
    for (int k = 0; k < EPT; k++) {
        int off = tid + k * SB;
        if (off < EPBK) {
            int e = e0 + off;
            unsigned hop = (unsigned)e / N_EDGES;
            int r = e - (int)hop * N_EDGES;
            const int* sp = ei + (size_t)hop * 2 * N_EDGES;
            int src = __builtin_nontemporal_load(sp + r);
            int dst = __builtin_nontemporal_load(sp + N_EDGES + r);
            float wv = __builtin_nontemporal_load(ew + (size_t)hop * N_EDGES + r);
            float pwh = hop == 0 ? pw1 : (hop == 1 ? pw2 : pw3);
            unsigned b = (unsigned)src / RB;
            bkt[k] = b;
            rec[k] = ((unsigned)f2bf_rne(pwh * wv) << 16) |
                     (unsigned)(((unsigned)src - b * RB) * 64 + batch[dst]);
            atomicAdd(&cnt[b], 1u);
        } else {
            bkt[k] = 0xFFFFFFFFu;
        }
    }
    __syncthreads();
    if (tid < NB) {
        unsigned c = cnt[tid];
        basearr[tid] = c ? atomicAdd(&cursors[sh * NB + tid], c) : 0u;
        cnt[tid] = 0u;  // reuse as within-block placement counter
    }
    __syncthreads();
#pragma unroll
    for (int k = 0; k < EPT; k++) {
        if (bkt[k] != 0xFFFFFFFFu) {
            unsigned o = atomicAdd(&cnt[bkt[k]], 1u);
            records[((size_t)sh * NB + bkt[k]) * CAP + basearr[bkt[k]] + o] = rec[k];
        }
    }
}

// ---- Phase B: one block per bucket. LDS f32 tile [160][65] (slot = m+(m>>6)).
// Replays records (uint4 loads) with LDS atomics, adds pw0 term, emits ct
// (MFMA-A bf16 layout) + tg column sums. coeff never touches HBM.
__global__ __launch_bounds__(512) void phaseB_kernel(
    const int* __restrict__ batch, const float* __restrict__ pw,
    const unsigned* __restrict__ cursors, const unsigned* __restrict__ records,
    unsigned short* __restrict__ ct, float* __restrict__ tg) {
    __shared__ float tile[RB * 65];
    const int tid = threadIdx.x;
    const int b = blockIdx.x;

    for (int i = tid; i < RB * 65; i += 512) tile[i] = 0.f;
    __syncthreads();

    if (tid < RB) atomicAdd(&tile[tid * 65 + batch[b * RB + tid]], pw[0]);

    for (int sh = 0; sh < NSH; sh++) {
        unsigned n = cursors[sh * NB + b];
        const unsigned* rp = records + ((size_t)sh * NB + b) * CAP;
        unsigned n4 = n >> 2;
        for (unsigned i = tid; i < n4; i += 512) {
            uint4 r4 = *(const uint4*)(rp + 4 * i);
            unsigned m0 = r4.x & 0x3FFFu, m1 = r4.y & 0x3FFFu;
            unsigned m2 = r4.z & 0x3FFFu, m3 = r4.w & 0x3FFFu;
            atomicAdd(&tile[m0 + (m0 >> 6)], bf2f((unsigned short)(r4.x >> 16)));
            atomicAdd(&tile[m1 + (m1 >> 6)], bf2f((unsigned short)(r4.y >> 16)));
            atomicAdd(&tile[m2 + (m2 >> 6)], bf2f((unsigned short)(r4.z >> 16)));
            atomicAdd(&tile[m3 + (m3 >> 6)], bf2f((unsigned short)(r4.w >> 16)));
        }
        unsigned i = 4 * n4 + tid;
        if (i < n) {
            unsigned r = rp[i];
            unsigned m = r & 0x3FFFu;
            atomicAdd(&tile[m + (m >> 6)], bf2f((unsigned short)(r >> 16)));
        }
    }
    __syncthreads();

    if (tid < 256) {
        const int gt = tid >> 6, l = tid & 63, q = l >> 4, c = l & 15;
        for (int cc = 0; cc < 5; cc++) {
            s16x8 v;
#pragma unroll
            for (int j = 0; j < 8; j++)
                v[j] = (short)f2bf_rne(tile[(cc * 32 + 8 * q + j) * 65 + 16 * gt + c]);
            *(s16x8*)&ct[(((size_t)(b * 5 + cc) * 4 + gt) * 64 + l) * 8] = v;
        }
    }
    if (tid < 64) {
        float sum = 0.f;
        for (int s = 0; s < RB; s++) sum += tile[s * 65 + tid];
        atomicAdd(&tg[tid], sum);
    }
}

// ---- Fused MFMA kernel: per 32-node chunk,
//   U = relu(X@W1 + b1)   (W1 B-frags persistent in registers)
//   S += Ct^T @ U
__global__ __launch_bounds__(256, 2) void fused_kernel(
    const float* __restrict__ x,
    const float* __restrict__ w1,
    const float* __restrict__ b1,
    const unsigned short* __restrict__ ct,
    unsigned short* __restrict__ s_part) {

    __shared__ __align__(16) unsigned short Ut[256 * 40];     // 20 KB
    __shared__ __align__(16) unsigned short x_lds[32 * 136];  // 8.7 KB
    __shared__ __align__(16) unsigned short ct_lds[2048];     // 4 KB

    const int tid = threadIdx.x;
    const int w = tid >> 6, l = tid & 63, q = l >> 4, c = l & 15;
    const int wcol = w * 64;
    const int sr = tid >> 3, sk = (tid & 7) * 16;

    s16x8 w1f[4][4];
#pragma unroll
    for (int nt = 0; nt < 4; nt++)
#pragma unroll
        for (int ks = 0; ks < 4; ks++) {
            s16x8 v;
#pragma unroll
            for (int j = 0; j < 8; j++)
                v[j] = (short)f2bf_rne(w1[(size_t)(32 * ks + 8 * q + j) * 256 + wcol + 16 * nt + c]);
            w1f[nt][ks] = v;
        }

    float bias[4];
#pragma unroll
    for (int nt = 0; nt < 4; nt++) bias[nt] = b1[wcol + 16 * nt + c];

    f32x4 sacc[4][4];
#pragma unroll
    for (int gt = 0; gt < 4; gt++)
#pragma unroll
        for (int nt = 0; nt < 4; nt++) sacc[gt][nt] = (f32x4)0.f;

    uint4 xp0, xp1;
    s16x8 ctp;

#define PREF(CI)                                                              \
    {                                                                         \
        const float4* p = (const float4*)&x[(size_t)((CI) * 32 + sr) * 128 + sk]; \
        float4 v0 = p[0], v1 = p[1], v2 = p[2], v3 = p[3];                    \
        xp0.x = pk_rne(v0.x, v0.y); xp0.y = pk_rne(v0.z, v0.w);               \
        xp0.z = pk_rne(v1.x, v1.y); xp0.w = pk_rne(v1.z, v1.w);               \
        xp1.x = pk_rne(v2.x, v2.y); xp1.y = pk_rne(v2.z, v2.w);               \
        xp1.z = pk_rne(v3.x, v3.y); xp1.w = pk_rne(v3.z, v3.w);               \
        ctp = *(const s16x8*)&ct[(size_t)(CI) * 2048 + tid * 8];              \
    }

    int ci = blockIdx.x;
    if (ci < NCHUNK) PREF(ci);

    for (; ci < NCHUNK; ci += FG) {
        *(uint4*)&x_lds[sr * 136 + sk] = xp0;
        *(uint4*)&x_lds[sr * 136 + sk + 8] = xp1;
        *(s16x8*)&ct_lds[tid * 8] = ctp;
        __syncthreads();

        s16x8 af[2][4], ctf[4];
#pragma unroll
        for (int mt = 0; mt < 2; mt++)
#pragma unroll
            for (int ks = 0; ks < 4; ks++)
                af[mt][ks] = *(const s16x8*)&x_lds[(16 * mt + c) * 136 + 32 * ks + 8 * q];
#pragma unroll
        for (int gt = 0; gt < 4; gt++)
            ctf[gt] = *(const s16x8*)&ct_lds[(gt * 64 + l) * 8];
        __syncthreads();

        if (ci + FG < NCHUNK) PREF(ci + FG);

        f32x4 u[2][4];
#pragma unroll
        for (int mt = 0; mt < 2; mt++)
#pragma unroll
            for (int nt = 0; nt < 4; nt++) {
                f32x4 a; a[0] = a[1] = a[2] = a[3] = bias[nt];
                u[mt][nt] = a;
            }
#pragma unroll
        for (int ks = 0; ks < 4; ks++)
#pragma unroll
            for (int mt = 0; mt < 2; mt++)
#pragma unroll
                for (int nt = 0; nt < 4; nt++)
                    u[mt][nt] = __builtin_amdgcn_mfma_f32_16x16x32_bf16(
                        af[mt][ks], w1f[nt][ks], u[mt][nt], 0, 0, 0);

#pragma unroll
        for (int mt = 0; mt < 2; mt++)
#pragma unroll
            for (int nt = 0; nt < 4; nt++) {
                f32x4 v = u[mt][nt];
                uint2 d;
                d.x = pk_rne(fmaxf(v[0], 0.f), fmaxf(v[1], 0.f));
                d.y = pk_rne(fmaxf(v[2], 0.f), fmaxf(v[3], 0.f));
                *(uint2*)&Ut[(wcol + 16 * nt + c) * 40 + 16 * mt + 4 * q] = d;
            }

#pragma unroll
        for (int nt = 0; nt < 4; nt++) {
            s16x8 uf = *(const s16x8*)&Ut[(wcol + 16 * nt + c) * 40 + 8 * q];
#pragma unroll
            for (int gt = 0; gt < 4; gt++)
                sacc[gt][nt] = __builtin_amdgcn_mfma_f32_16x16x32_bf16(
                    ctf[gt], uf, sacc[gt][nt], 0, 0, 0);
        }
    }
#undef PREF

    unsigned short* my = s_part + (size_t)blockIdx.x * (64 * 256);
#pragma unroll
    for (int gt = 0; gt < 4; gt++)
#pragma unroll
        for (int nt = 0; nt < 4; nt++)
#pragma unroll
            for (int r = 0; r < 4; r++)
                my[(16 * gt + 4 * q + r) * 256 + wcol + 16 * nt + c] =
                    f2bf_rne(sacc[gt][nt][r]);
}

// 256 blocks: element range split 64-wide, FG dim split 4-way for parallelism
__global__ __launch_bounds__(256) void reduce_kernel(const unsigned short* __restrict__ s_part,
                                                     float* __restrict__ s_sum) {
    __shared__ float red[4][64];
    const int l = threadIdx.x & 63, p = threadIdx.x >> 6;
    const int e = blockIdx.x * 64 + l;
    float a0 = 0.f, a1 = 0.f, a2 = 0.f, a3 = 0.f;
    for (int b = p * (FG / 4); b < (p + 1) * (FG / 4); b += 4) {
        a0 += bf2f(s_part[(size_t)(b + 0) * 16384 + e]);
        a1 += bf2f(s_part[(size_t)(b + 1) * 16384 + e]);
        a2 += bf2f(s_part[(size_t)(b + 2) * 16384 + e]);
        a3 += bf2f(s_part[(size_t)(b + 3) * 16384 + e]);
    }
    red[p][l] = (a0 + a1) + (a2 + a3);
    __syncthreads();
    if (p == 0) s_sum[e] = (red[0][l] + red[1][l]) + (red[2][l] + red[3][l]);
}

__global__ void finalize_kernel(const float* __restrict__ s,
                                const float* __restrict__ t,
                                const float* __restrict__ w2,
                                const float* __restrict__ b2,
                                float* __restrict__ out) {
    __shared__ float red[128];
    const int g = blockIdx.x;
    const int f = threadIdx.x;

    float acc = t[g] * b2[f];
    for (int k = 0; k < D_HID; k++)
        acc += s[(size_t)g * 256 + k] * w2[(size_t)k * 128 + f];

    red[f] = acc;
    __syncthreads();
    for (int off = 64; off > 0; off >>= 1) {
        if (f < off) red[f] = fmaxf(red[f], red[f + off]);
        __syncthreads();
    }
    float mx = red[0];
    __syncthreads();
    red[f] = expf(acc - mx);
    __syncthreads();
    for (int off = 64; off > 0; off >>= 1) {
        if (f < off) red[f] += red[f + off];
        __syncthreads();
    }
    float lse = logf(red[0]);
    out[(size_t)g * 128 + f] = acc - mx - lse;
}

extern "C" void kernel_launch(void* const* d_in, const int* in_sizes, int n_in,
                              void* d_out, int out_size, void* d_ws, size_t ws_size,
                              hipStream_t stream) {
    const float* x     = (const float*)d_in[0];
    const int*   ei    = (const int*)d_in[1];
    const float* ew    = (const float*)d_in[2];
    const int*   batch = (const int*)d_in[3];
    const float* w1    = (const float*)d_in[4];
    const float* b1    = (const float*)d_in[5];
    const float* w2    = (const float*)d_in[6];
    const float* b2    = (const float*)d_in[7];
    const float* pw    = (const float*)d_in[8];
    float* out = (float*)d_out;

    unsigned short* ctp     = (unsigned short*)((char*)d_ws + CT_OFF);
    unsigned*       records = (unsigned*)((char*)d_ws + REC_OFF);
    unsigned short* s_part  = (unsigned short*)((char*)d_ws + SPART_OFF);
    unsigned*       cursors = (unsigned*)((char*)d_ws + CUR_OFF);
    float*          tgp     = (float*)((char*)d_ws + TG_OFF);
    float*          s_sum   = (float*)((char*)d_ws + SSUM_OFF);

    hipMemsetAsync(cursors, 0, NSH * NB * sizeof(unsigned), stream);
    hipMemsetAsync(tgp, 0, 64 * sizeof(float), stream);

    scatter_kernel<<<dim3(SGRID), SB, 0, stream>>>(
        ei, ew, batch, pw, cursors, records);
    phaseB_kernel<<<dim3(NB), 512, 0, stream>>>(batch, pw, cursors, records, ctp, tgp);
    fused_kernel<<<dim3(FG), 256, 0, stream>>>(x, w1, b1, ctp, s_part);
    reduce_kernel<<<dim3(256), 256, 0, stream>>>(s_part, s_sum);
    finalize_kernel<<<dim3(64), 128, 0, stream>>>(s_sum, tgp, w2, b2, out);
}

// Round 9
// 250.150 us; speedup vs baseline: 1.2725x; 1.0245x over previous
//
#include <hip/hip_runtime.h>
#include <hip/hip_bf16.h>

#define N_NODES 100000
#define N_EDGES 1600000
#define N_HOPS 3
#define D_HID 256
#define N_GRAPHS 64

#define CHUNK 32
#define NCHUNK 3125          /* 100000/32 */
#define FG 512               /* fused grid */

#define NB 625               /* node buckets */
#define RB 160               /* nodes per bucket (5 chunks) */
#define NSH 4                /* cursor shadows */
#define CAP 2400             /* record capacity per (shadow,bucket); mean 1920, sigma~44 */
#define SGRID 500            /* scatter blocks (~2/CU, one round) */
#define SB 1024              /* scatter block threads (16 waves) */
#define I4PB 2400            /* int4 edge-groups per block: 500*2400*4 = 4.8M edges exact */
#define NI4H 400000          /* int4 groups per hop */

// ws layout (total ~37.0 MB):
//  [0, 12.8MB)        ct bf16 A-frag [NCHUNK][4][64][8]
//  [12.8MB, 36.8MB)   records u32 [NSH][NB][CAP] = 24.0MB   (phase A/B)
//    overlay: s_part bf16 [FG][64*256] = 16.8MB             (fused onward)
//  [36.8MB, ...)      cursors u32[NSH*NB] | tg f32[64] | s_sum f32[16384] | w1p bf16[32768]
#define CT_OFF    0u
#define REC_OFF   12800000u
#define SPART_OFF REC_OFF
#define SMALL_OFF 36800000u
#define CUR_OFF   SMALL_OFF
#define TG_OFF    (SMALL_OFF + 16384u)
#define SSUM_OFF  (SMALL_OFF + 32768u)
#define W1P_OFF   (SMALL_OFF + 131072u)

typedef __attribute__((ext_vector_type(4))) float f32x4;
typedef __attribute__((ext_vector_type(8))) short s16x8;
typedef __attribute__((ext_vector_type(4))) int i32x4;
typedef __attribute__((ext_vector_type(4))) float fv4;

__device__ __forceinline__ unsigned short f2bf_rne(float f) {
    union { float f; unsigned u; } v; v.f = f;
    unsigned r = v.u + 0x7FFFu + ((v.u >> 16) & 1u);
    return (unsigned short)(r >> 16);
}
__device__ __forceinline__ float bf2f(unsigned short s) {
    union { float f; unsigned u; } v; v.u = ((unsigned)s) << 16;
    return v.f;
}
__device__ __forceinline__ unsigned pk_rne(float lo, float hi) {
    return ((unsigned)f2bf_rne(hi) << 16) | (unsigned)f2bf_rne(lo);
}

// ---- W1 fragment pre-pack: w1p[(tid*16 + nt*4+ks)*8 + j] =
//   bf16(w1[(32ks+8q+j)*256 + w*64+16nt+c]),  tid=fused thread, w=tid>>6 etc.
// Kills fused's 16.7M scattered scalar w1 loads (round-7 invisible sink).
__global__ __launch_bounds__(256) void w1_prep(const float* __restrict__ w1,
                                               unsigned short* __restrict__ w1p) {
    int f = blockIdx.x * 256 + threadIdx.x;   // 0..4095
    int t = f >> 4, fr = f & 15, nt = fr >> 2, ks = fr & 3;
    int w = t >> 6, l = t & 63, q = l >> 4, c = l & 15;
    s16x8 v;
#pragma unroll
    for (int j = 0; j < 8; j++)
        v[j] = (short)f2bf_rne(w1[(size_t)(32 * ks + 8 * q + j) * 256 + w * 64 + 16 * nt + c]);
    *(s16x8*)&w1p[(size_t)f * 8] = v;
}

// ---- Phase A: bin edges into per-(shadow,bucket) record ranges.
// Single-pass, register-buffered (12 edges/thread), ext-vector NON-TEMPORAL
// edge-stream loads (NT keeps partial record lines L2-resident — twice-proven;
// vectorization cuts stream VMEM issue 3x vs round 7). One dispatch round.
__global__ __launch_bounds__(SB) void scatter_kernel(
    const int* __restrict__ ei, const float* __restrict__ ew,
    const int* __restrict__ batch, const float* __restrict__ pw,
    unsigned* __restrict__ cursors, unsigned* __restrict__ records) {
    __shared__ unsigned cnt[NB], basearr[NB];
    const int tid = threadIdx.x;
    const int sh = blockIdx.x & (NSH - 1);
    const int i40 = blockIdx.x * I4PB;

    if (tid < NB) cnt[tid] = 0u;
    __syncthreads();

    const float pw1 = pw[1], pw2 = pw[2], pw3 = pw[3];

    unsigned rec[12], bkt[12];
#pragma unroll
    for (int k = 0; k < 3; k++) {
        int idx = tid + k * SB;
        if (idx < I4PB) {
            int i4 = i40 + idx;
            unsigned hop = (unsigned)i4 / NI4H;
            int r4 = i4 - (int)hop * NI4H;
            const i32x4* sp4 = (const i32x4*)(ei + (size_t)hop * 2 * N_EDGES);
            i32x4 s = __builtin_nontemporal_load(sp4 + r4);
            i32x4 d = __builtin_nontemporal_load(sp4 + NI4H + r4);
            fv4 wv = __builtin_nontemporal_load((const fv4*)(ew + (size_t)hop * N_EDGES) + r4);
            float pwh = hop == 0 ? pw1 : (hop == 1 ? pw2 : pw3);
#pragma unroll
            for (int j = 0; j < 4; j++) {
                unsigned b = (unsigned)s[j] / RB;
                bkt[k * 4 + j] = b;
                rec[k * 4 + j] = ((unsigned)f2bf_rne(pwh * wv[j]) << 16) |
                                 (unsigned)(((unsigned)s[j] - b * RB) * 64 + batch[d[j]]);
                atomicAdd(&cnt[b], 1u);
            }
        } else {
#pragma unroll
            for (int j = 0; j < 4; j++) bkt[k * 4 + j] = 0xFFFFFFFFu;
        }
    }
    __syncthreads();
    if (tid < NB) {
        unsigned c = cnt[tid];
        basearr[tid] = c ? atomicAdd(&cursors[sh * NB + tid], c) : 0u;
        cnt[tid] = 0u;  // reuse as within-block placement counter
    }
    __syncthreads();
#pragma unroll
    for (int k = 0; k < 12; k++) {
        if (bkt[k] != 0xFFFFFFFFu) {
            unsigned o = atomicAdd(&cnt[bkt[k]], 1u);
            records[((size_t)sh * NB + bkt[k]) * CAP + basearr[bkt[k]] + o] = rec[k];
        }
    }
}

// ---- Phase B: one block per bucket. LDS f32 tile [160][65] (slot = m+(m>>6)).
// Replays records (uint4 loads) with LDS atomics, adds pw0 term, emits ct
// (MFMA-A bf16 layout) + tg column sums. coeff never touches HBM.
__global__ __launch_bounds__(512) void phaseB_kernel(
    const int* __restrict__ batch, const float* __restrict__ pw,
    const unsigned* __restrict__ cursors, const unsigned* __restrict__ records,
    unsigned short* __restrict__ ct, float* __restrict__ tg) {
    __shared__ float tile[RB * 65];
    const int tid = threadIdx.x;
    const int b = blockIdx.x;

    for (int i = tid; i < RB * 65; i += 512) tile[i] = 0.f;
    __syncthreads();

    if (tid < RB) atomicAdd(&tile[tid * 65 + batch[b * RB + tid]], pw[0]);

    for (int sh = 0; sh < NSH; sh++) {
        unsigned n = cursors[sh * NB + b];
        const unsigned* rp = records + ((size_t)sh * NB + b) * CAP;
        unsigned n4 = n >> 2;
        for (unsigned i = tid; i < n4; i += 512) {
            uint4 r4 = *(const uint4*)(rp + 4 * i);
            unsigned m0 = r4.x & 0x3FFFu, m1 = r4.y & 0x3FFFu;
            unsigned m2 = r4.z & 0x3FFFu, m3 = r4.w & 0x3FFFu;
            atomicAdd(&tile[m0 + (m0 >> 6)], bf2f((unsigned short)(r4.x >> 16)));
            atomicAdd(&tile[m1 + (m1 >> 6)], bf2f((unsigned short)(r4.y >> 16)));
            atomicAdd(&tile[m2 + (m2 >> 6)], bf2f((unsigned short)(r4.z >> 16)));
            atomicAdd(&tile[m3 + (m3 >> 6)], bf2f((unsigned short)(r4.w >> 16)));
        }
        unsigned i = 4 * n4 + tid;
        if (i < n) {
            unsigned r = rp[i];
            unsigned m = r & 0x3FFFu;
            atomicAdd(&tile[m + (m >> 6)], bf2f((unsigned short)(r >> 16)));
        }
    }
    __syncthreads();

    if (tid < 256) {
        const int gt = tid >> 6, l = tid & 63, q = l >> 4, c = l & 15;
        for (int cc = 0; cc < 5; cc++) {
            s16x8 v;
#pragma unroll
            for (int j = 0; j < 8; j++)
                v[j] = (short)f2bf_rne(tile[(cc * 32 + 8 * q + j) * 65 + 16 * gt + c]);
            *(s16x8*)&ct[(((size_t)(b * 5 + cc) * 4 + gt) * 64 + l) * 8] = v;
        }
    }
    if (tid < 64) {
        float sum = 0.f;
        for (int s = 0; s < RB; s++) sum += tile[s * 65 + tid];
        atomicAdd(&tg[tid], sum);
    }
}

// ---- Fused MFMA kernel: per 32-node chunk,
//   U = relu(X@W1 + b1)   (W1 frags from w1p, coalesced)
//   S += Ct^T @ U
__global__ __launch_bounds__(256, 2) void fused_kernel(
    const float* __restrict__ x,
    const unsigned short* __restrict__ w1p,
    const float* __restrict__ b1,
    const unsigned short* __restrict__ ct,
    unsigned short* __restrict__ s_part) {

    __shared__ __align__(16) unsigned short Ut[256 * 40];     // 20 KB
    __shared__ __align__(16) unsigned short x_lds[32 * 136];  // 8.7 KB
    __shared__ __align__(16) unsigned short ct_lds[2048];     // 4 KB

    const int tid = threadIdx.x;
    const int w = tid >> 6, l = tid & 63, q = l >> 4, c = l & 15;
    const int wcol = w * 64;
    const int sr = tid >> 3, sk = (tid & 7) * 16;

    // W1 B-fragments: pre-packed, 16 coalesced 16B loads
    s16x8 w1f[4][4];
    {
        const s16x8* wp = (const s16x8*)(w1p + (size_t)tid * 128);
#pragma unroll
        for (int nt = 0; nt < 4; nt++)
#pragma unroll
            for (int ks = 0; ks < 4; ks++)
                w1f[nt][ks] = wp[nt * 4 + ks];
    }

    float bias[4];
#pragma unroll
    for (int nt = 0; nt < 4; nt++) bias[nt] = b1[wcol + 16 * nt + c];

    f32x4 sacc[4][4];
#pragma unroll
    for (int gt = 0; gt < 4; gt++)
#pragma unroll
        for (int nt = 0; nt < 4; nt++) sacc[gt][nt] = (f32x4)0.f;

    uint4 xp0, xp1;
    s16x8 ctp;

#define PREF(CI)                                                              \
    {                                                                         \
        const float4* p = (const float4*)&x[(size_t)((CI) * 32 + sr) * 128 + sk]; \
        float4 v0 = p[0], v1 = p[1], v2 = p[2], v3 = p[3];                    \
        xp0.x = pk_rne(v0.x, v0.y); xp0.y = pk_rne(v0.z, v0.w);               \
        xp0.z = pk_rne(v1.x, v1.y); xp0.w = pk_rne(v1.z, v1.w);               \
        xp1.x = pk_rne(v2.x, v2.y); xp1.y = pk_rne(v2.z, v2.w);               \
        xp1.z = pk_rne(v3.x, v3.y); xp1.w = pk_rne(v3.z, v3.w);               \
        ctp = *(const s16x8*)&ct[(size_t)(CI) * 2048 + tid * 8];              \
    }

    int ci = blockIdx.x;
    if (ci < NCHUNK) PREF(ci);

    for (; ci < NCHUNK; ci += FG) {
        *(uint4*)&x_lds[sr * 136 + sk] = xp0;
        *(uint4*)&x_lds[sr * 136 + sk + 8] = xp1;
        *(s16x8*)&ct_lds[tid * 8] = ctp;
        __syncthreads();

        s16x8 af[2][4], ctf[4];
#pragma unroll
        for (int mt = 0; mt < 2; mt++)
#pragma unroll
            for (int ks = 0; ks < 4; ks++)
                af[mt][ks] = *(const s16x8*)&x_lds[(16 * mt + c) * 136 + 32 * ks + 8 * q];
#pragma unroll
        for (int gt = 0; gt < 4; gt++)
            ctf[gt] = *(const s16x8*)&ct_lds[(gt * 64 + l) * 8];
        __syncthreads();

        if (ci + FG < NCHUNK) PREF(ci + FG);

        f32x4 u[2][4];
#pragma unroll
        for (int mt = 0; mt < 2; mt++)
#pragma unroll
            for (int nt = 0; nt < 4; nt++) {
                f32x4 a; a[0] = a[1] = a[2] = a[3] = bias[nt];
                u[mt][nt] = a;
            }
#pragma unroll
        for (int ks = 0; ks < 4; ks++)
#pragma unroll
            for (int mt = 0; mt < 2; mt++)
#pragma unroll
                for (int nt = 0; nt < 4; nt++)
                    u[mt][nt] = __builtin_amdgcn_mfma_f32_16x16x32_bf16(
                        af[mt][ks], w1f[nt][ks], u[mt][nt], 0, 0, 0);

#pragma unroll
        for (int mt = 0; mt < 2; mt++)
#pragma unroll
            for (int nt = 0; nt < 4; nt++) {
                f32x4 v = u[mt][nt];
                uint2 d;
                d.x = pk_rne(fmaxf(v[0], 0.f), fmaxf(v[1], 0.f));
                d.y = pk_rne(fmaxf(v[2], 0.f), fmaxf(v[3], 0.f));
                *(uint2*)&Ut[(wcol + 16 * nt + c) * 40 + 16 * mt + 4 * q] = d;
            }

#pragma unroll
        for (int nt = 0; nt < 4; nt++) {
            s16x8 uf = *(const s16x8*)&Ut[(wcol + 16 * nt + c) * 40 + 8 * q];
#pragma unroll
            for (int gt = 0; gt < 4; gt++)
                sacc[gt][nt] = __builtin_amdgcn_mfma_f32_16x16x32_bf16(
                    ctf[gt], uf, sacc[gt][nt], 0, 0, 0);
        }
    }
#undef PREF

    unsigned short* my = s_part + (size_t)blockIdx.x * (64 * 256);
#pragma unroll
    for (int gt = 0; gt < 4; gt++)
#pragma unroll
        for (int nt = 0; nt < 4; nt++)
#pragma unroll
            for (int r = 0; r < 4; r++)
                my[(16 * gt + 4 * q + r) * 256 + wcol + 16 * nt + c] =
                    f2bf_rne(sacc[gt][nt][r]);
}

// 256 blocks: element range split 64-wide, FG dim split 4-way for parallelism
__global__ __launch_bounds__(256) void reduce_kernel(const unsigned short* __restrict__ s_part,
                                                     float* __restrict__ s_sum) {
    __shared__ float red[4][64];
    const int l = threadIdx.x & 63, p = threadIdx.x >> 6;
    const int e = blockIdx.x * 64 + l;
    float a0 = 0.f, a1 = 0.f, a2 = 0.f, a3 = 0.f;
    for (int b = p * (FG / 4); b < (p + 1) * (FG / 4); b += 4) {
        a0 += bf2f(s_part[(size_t)(b + 0) * 16384 + e]);
        a1 += bf2f(s_part[(size_t)(b + 1) * 16384 + e]);
        a2 += bf2f(s_part[(size_t)(b + 2) * 16384 + e]);
        a3 += bf2f(s_part[(size_t)(b + 3) * 16384 + e]);
    }
    red[p][l] = (a0 + a1) + (a2 + a3);
    __syncthreads();
    if (p == 0) s_sum[e] = (red[0][l] + red[1][l]) + (red[2][l] + red[3][l]);
}

__global__ void finalize_kernel(const float* __restrict__ s,
                                const float* __restrict__ t,
                                const float* __restrict__ w2,
                                const float* __restrict__ b2,
                                float* __restrict__ out) {
    __shared__ float red[128];
    const int g = blockIdx.x;
    const int f = threadIdx.x;

    float acc = t[g] * b2[f];
    for (int k = 0; k < D_HID; k++)
        acc += s[(size_t)g * 256 + k] * w2[(size_t)k * 128 + f];

    red[f] = acc;
    __syncthreads();
    for (int off = 64; off > 0; off >>= 1) {
        if (f < off) red[f] = fmaxf(red[f], red[f + off]);
        __syncthreads();
    }
    float mx = red[0];
    __syncthreads();
    red[f] = expf(acc - mx);
    __syncthreads();
    for (int off = 64; off > 0; off >>= 1) {
        if (f < off) red[f] += red[f + off];
        __syncthreads();
    }
    float lse = logf(red[0]);
    out[(size_t)g * 128 + f] = acc - mx - lse;
}

extern "C" void kernel_launch(void* const* d_in, const int* in_sizes, int n_in,
                              void* d_out, int out_size, void* d_ws, size_t ws_size,
                              hipStream_t stream) {
    const float* x     = (const float*)d_in[0];
    const int*   ei    = (const int*)d_in[1];
    const float* ew    = (const float*)d_in[2];
    const int*   batch = (const int*)d_in[3];
    const float* w1    = (const float*)d_in[4];
    const float* b1    = (const float*)d_in[5];
    const float* w2    = (const float*)d_in[6];
    const float* b2    = (const float*)d_in[7];
    const float* pw    = (const float*)d_in[8];
    float* out = (float*)d_out;

    unsigned short* ctp     = (unsigned short*)((char*)d_ws + CT_OFF);
    unsigned*       records = (unsigned*)((char*)d_ws + REC_OFF);
    unsigned short* s_part  = (unsigned short*)((char*)d_ws + SPART_OFF);
    unsigned*       cursors = (unsigned*)((char*)d_ws + CUR_OFF);
    float*          tgp     = (float*)((char*)d_ws + TG_OFF);
    float*          s_sum   = (float*)((char*)d_ws + SSUM_OFF);
    unsigned short* w1pp    = (unsigned short*)((char*)d_ws + W1P_OFF);

    hipMemsetAsync(cursors, 0, NSH * NB * sizeof(unsigned), stream);
    hipMemsetAsync(tgp, 0, 64 * sizeof(float), stream);

    w1_prep<<<dim3(16), 256, 0, stream>>>(w1, w1pp);
    scatter_kernel<<<dim3(SGRID), SB, 0, stream>>>(
        ei, ew, batch, pw, cursors, records);
    phaseB_kernel<<<dim3(NB), 512, 0, stream>>>(batch, pw, cursors, records, ctp, tgp);
    fused_kernel<<<dim3(FG), 256, 0, stream>>>(x, w1pp, b1, ctp, s_part);
    reduce_kernel<<<dim3(256), 256, 0, stream>>>(s_part, s_sum);
    finalize_kernel<<<dim3(64), 128, 0, stream>>>(s_sum, tgp, w2, b2, out);
}